// Round 1
// 297.400 us; speedup vs baseline: 1.0423x; 1.0423x over previous
//
#include <hip/hip_runtime.h>

// Problem constants
#define B_ 2
#define N_ 196608
#define K_ 9
#define F_ 64
#define ROWS 64   // n-rows per block
#define ROWB 256  // bytes per xb row (both batch planes: [n][2][64] bf16)

typedef __attribute__((ext_vector_type(8))) short short8;
typedef __attribute__((ext_vector_type(4))) unsigned short ushort4v;
typedef __attribute__((ext_vector_type(4))) float f32x4;

__device__ __forceinline__ unsigned short f2bf(float f) {
  unsigned u = __builtin_bit_cast(unsigned, f);
  u = (u + 0x7fffu + ((u >> 16) & 1u)) >> 16;  // RNE
  return (unsigned short)u;
}

// x fp32 [B][N][64] -> xb bf16 [N][B][64]. Fully coalesced: thread = one 16B chunk.
// Wave reads 1 KB contiguous, writes 512 B contiguous. grid (N*16/256, B).
__global__ __launch_bounds__(256) void cvt_x_kernel(const float* __restrict__ x,
                                                    unsigned short* __restrict__ xb) {
  const int b = blockIdx.y;
  const long cidx = (long)blockIdx.x * 256 + threadIdx.x;  // 16B-chunk id within plane
  const long n = cidx >> 4;
  const int qd = (int)(cidx & 15);
  const float4 v = *(const float4*)(x + ((size_t)b * N_ + n) * F_ + (size_t)qd * 4);
  ushort4v r;
  r[0] = f2bf(v.x); r[1] = f2bf(v.y); r[2] = f2bf(v.z); r[3] = f2bf(v.w);
  *(ushort4v*)(xb + ((size_t)n * 2 + b) * F_ + qd * 4) = r;
}

// W fp32 [9][64][64] (k,f,o) -> Wt bf16 [9][64][64] (k,o,f)
__global__ __launch_bounds__(256) void cvt_w_kernel(const float* __restrict__ W,
                                                    unsigned short* __restrict__ wt) {
  const int i = blockIdx.x * 256 + threadIdx.x;
  const int k = i >> 12;
  const int rem = i & 4095;
  const int o = rem >> 6;
  const int f = rem & 63;
  wt[i] = f2bf(W[(k << 12) + (f << 6) + o]);
}

// Main: 256 thr (4 waves). Each wave owns rows [w*16, w*16+16): it stages them AND
// consumes them -> no cross-wave sharing -> ZERO barriers. Per-wave 3-buffer DMA
// pipeline (depth 2) with hand-counted s_waitcnt vmcnt(N); wt B-frags prefetched one
// k ahead into registers so compiler reg-waits never drain the gather queue.
__global__ __launch_bounds__(256, 3) void nhconv_main(
    const short* __restrict__ xb,    // [N][2][64] bf16 bits, 256 B per n
    const int* __restrict__ adjc,    // [N][9] int32
    const short* __restrict__ wt,    // [9][64][64] bf16 bits, Wt[k][o][f]
    const float* __restrict__ bias,  // [64]
    float* __restrict__ out) {       // [2][N][64] fp32
  __shared__ short abuf[3][ROWS * 128];  // 3 x 16 KB gathered A tiles (wave-private rows)
  __shared__ int s_adj[ROWS * K_];       // 2304 B (wave-private sections)

  const int tid = (int)threadIdx.x;
  const int n0 = blockIdx.x * ROWS;
  const int w = tid >> 6;  // wave 0..3
  const int l = tid & 63;  // lane
  const int q = l >> 4;    // quad 0..3
  const int c = l & 15;

  // Per-wave adjacency staging (wave-private section; wave-synchronous, no barrier).
  {
    const int base = w * (16 * K_);
    for (int i = l; i < 16 * K_; i += 64)
      s_adj[base + i] =
          __builtin_nontemporal_load(adjc + (size_t)(n0 + w * 16) * K_ + i);
  }

  // DMA stage: wave w moves its 16 rows of neighbor k into abuf[bf].
  // Each inst: 4 rows x 256 B; per-row XOR chunk swizzle on the GLOBAL side,
  // linear LDS dest (global_load_lds requirement).
  auto stage = [&](int k, int bf) {
#pragma unroll
    for (int j = 0; j < 4; ++j) {
      const int row = w * 16 + j * 4 + (l >> 4);
      const int src_chunk = (l & 15) ^ (row & 7);
      const size_t goff = (size_t)(unsigned)s_adj[row * K_ + k] * ROWB + (src_chunk << 4);
      const char* src = (const char*)xb + goff;
      short* dst = &abuf[bf][(w * 16 + j * 4) * 128];  // wave-uniform base
      __builtin_amdgcn_global_load_lds(
          (const __attribute__((address_space(1))) unsigned int*)src,
          (__attribute__((address_space(3))) unsigned int*)dst, 16, 0, 0);
    }
  };

  // wt B-fragment register prefetch (8 x short8 = 32 VGPR per set, ping-pong).
  const short* wbase = wt + q * 8 + (c << 6);
  short8 rw[2][8];
  auto wload = [&](int k, int par) {
#pragma unroll
    for (int fs = 0; fs < 2; ++fs)
#pragma unroll
      for (int ct = 0; ct < 4; ++ct)
        rw[par][fs * 4 + ct] = *(const short8*)(wbase + (k << 12) + fs * 32 + (ct << 10));
  };

  f32x4 acc[2][4];
#pragma unroll
  for (int p = 0; p < 2; ++p)
#pragma unroll
    for (int ct = 0; ct < 4; ++ct)
      acc[p][ct] = (f32x4){0.f, 0.f, 0.f, 0.f};

  // Prologue: W0, S0, W1, S1.  (adjc loads are drained by the compiler before the
  // s_adj ds_writes, which precede stage's s_adj ds_reads -> not in vmcnt flight here.)
  wload(0, 0);
  stage(0, 0);
  wload(1, 1);
  stage(1, 1);

  // Steady-state issue order per iter k:  [lgkm fence] W_{k+1}(8) S_{k+2}(4)
  //   s_waitcnt vmcnt(16)  -> 16 newest = {S_{k+1}, W_{k+1}, S_{k+2}} stay in flight,
  //   S_k + W_k guaranteed complete.  Tail: vmcnt(12) @k=7, vmcnt(0) @k=8.
#pragma unroll
  for (int k = 0; k < K_; ++k) {
    // Ensure my prior ds_reads fully completed before DMA may overwrite that buffer.
    asm volatile("s_waitcnt lgkmcnt(0)" ::: "memory");
    if (k >= 1 && k + 1 < K_) wload(k + 1, (k + 1) & 1);
    if (k + 2 < K_) stage(k + 2, (k + 2) % 3);

    if (k <= K_ - 3) {
      asm volatile("s_waitcnt vmcnt(16)" ::: "memory");
    } else if (k == K_ - 2) {
      asm volatile("s_waitcnt vmcnt(12)" ::: "memory");
    } else {
      asm volatile("s_waitcnt vmcnt(0)" ::: "memory");
    }
    __builtin_amdgcn_sched_barrier(0);

    const short* bufk = abuf[k % 3];
    const int arow = (w * 16 + c) * 128;  // this lane's A row base (shorts)
#pragma unroll
    for (int fs = 0; fs < 2; ++fs) {
      const int ch0 = (fs * 4 + q) ^ (c & 7);      // plane 0 chunk (swizzled)
      const int ch1 = (8 + fs * 4 + q) ^ (c & 7);  // plane 1 chunk
      const short8 a0 = *(const short8*)&bufk[arow + (ch0 << 3)];
      const short8 a1 = *(const short8*)&bufk[arow + (ch1 << 3)];
#pragma unroll
      for (int ct = 0; ct < 4; ++ct) {
        const short8 bfr = rw[k & 1][fs * 4 + ct];
        acc[0][ct] = __builtin_amdgcn_mfma_f32_16x16x32_bf16(a0, bfr, acc[0][ct], 0, 0, 0);
        acc[1][ct] = __builtin_amdgcn_mfma_f32_16x16x32_bf16(a1, bfr, acc[1][ct], 0, 0, 0);
      }
    }
  }

  // Epilogue: C col = lane&15, row = quad*4 + reg; nontemporal stores.
  float bv[4];
#pragma unroll
  for (int ct = 0; ct < 4; ++ct) bv[ct] = bias[ct * 16 + c];

#pragma unroll
  for (int p = 0; p < 2; ++p) {
    const size_t outbase = ((size_t)p * N_ + (size_t)(n0 + w * 16)) * F_;
#pragma unroll
    for (int ct = 0; ct < 4; ++ct) {
#pragma unroll
      for (int rr = 0; rr < 4; ++rr) {
        const int row = q * 4 + rr;
        __builtin_nontemporal_store(acc[p][ct][rr] + bv[ct],
                                    &out[outbase + (size_t)row * F_ + ct * 16 + c]);
      }
    }
  }
}

extern "C" void kernel_launch(void* const* d_in, const int* in_sizes, int n_in,
                              void* d_out, int out_size, void* d_ws, size_t ws_size,
                              hipStream_t stream) {
  const float* x = (const float*)d_in[0];
  const int* adjc = (const int*)d_in[1];
  const float* W = (const float*)d_in[2];
  const float* bias = (const float*)d_in[3];
  float* out = (float*)d_out;

  unsigned short* xb = (unsigned short*)d_ws;  // 50,331,648 B
  unsigned short* wt = (unsigned short*)((char*)d_ws + (size_t)B_ * N_ * F_ * 2);

  cvt_x_kernel<<<dim3(N_ * 16 / 256, B_), 256, 0, stream>>>(x, xb);
  cvt_w_kernel<<<144, 256, 0, stream>>>(W, wt);

  nhconv_main<<<N_ / ROWS, 256, 0, stream>>>((const short*)xb, adjc, (const short*)wt,
                                             bias, out);
}

// Round 2
// 263.547 us; speedup vs baseline: 1.1762x; 1.1285x over previous
//
#include <hip/hip_runtime.h>

// Problem constants
#define B_ 2
#define N_ 196608
#define K_ 9
#define F_ 64
#define ROWS 64   // n-rows per block == per wave (1-wave blocks, barrier-free)
#define ROWB 256  // bytes per xb row (both batch planes: [n][2][64] bf16)

typedef __attribute__((ext_vector_type(8))) short short8;
typedef __attribute__((ext_vector_type(4))) unsigned short ushort4v;
typedef __attribute__((ext_vector_type(4))) float f32x4;

__device__ __forceinline__ unsigned short f2bf(float f) {
  unsigned u = __builtin_bit_cast(unsigned, f);
  u = (u + 0x7fffu + ((u >> 16) & 1u)) >> 16;  // RNE
  return (unsigned short)u;
}

// x fp32 [B][N][64] -> xb bf16 [N][B][64]. Fully coalesced: thread = one 16B chunk.
__global__ __launch_bounds__(256) void cvt_x_kernel(const float* __restrict__ x,
                                                    unsigned short* __restrict__ xb) {
  const int b = blockIdx.y;
  const long cidx = (long)blockIdx.x * 256 + threadIdx.x;  // 16B-chunk id within plane
  const long n = cidx >> 4;
  const int qd = (int)(cidx & 15);
  const float4 v = *(const float4*)(x + ((size_t)b * N_ + n) * F_ + (size_t)qd * 4);
  ushort4v r;
  r[0] = f2bf(v.x); r[1] = f2bf(v.y); r[2] = f2bf(v.z); r[3] = f2bf(v.w);
  *(ushort4v*)(xb + ((size_t)n * 2 + b) * F_ + qd * 4) = r;
}

// W fp32 [9][64][64] (k,f,o) -> Wt bf16 [9][64][64] (k,o,f)
__global__ __launch_bounds__(256) void cvt_w_kernel(const float* __restrict__ W,
                                                    unsigned short* __restrict__ wt) {
  const int i = blockIdx.x * 256 + threadIdx.x;
  const int k = i >> 12;
  const int rem = i & 4095;
  const int o = rem >> 6;
  const int f = rem & 63;
  wt[i] = f2bf(W[(k << 12) + (f << 6) + o]);
}

// Main: ONE 64-lane wave per block owning 64 rows (both planes). Barrier-free.
// Rationale: the kernel is L2-request-rate bound (~0.26 64B-granules/cyc/CU); wt
// redundancy scales with wave count, so 4x rows/wave cuts wt requests 4x
// (14.2M -> 3.5M granules/dispatch). 3-buffer depth-2 DMA pipeline, counted vmcnt.
__global__ __launch_bounds__(64, 1) void nhconv_main(
    const short* __restrict__ xb,    // [N][2][64] bf16 bits, 256 B per n
    const int* __restrict__ adjc,    // [N][9] int32
    const short* __restrict__ wt,    // [9][64][64] bf16 bits, Wt[k][o][f]
    const float* __restrict__ bias,  // [64]
    float* __restrict__ out) {       // [2][N][64] fp32
  __shared__ short abuf[3][ROWS * 128];  // 3 x 16 KB gathered A tiles (wave-private)
  __shared__ int s_adj[ROWS * K_];       // 2304 B

  const int l = (int)threadIdx.x;  // lane
  const int n0 = blockIdx.x * ROWS;
  const int q = l >> 4;  // quad 0..3
  const int c = l & 15;

  // Wave-synchronous adjacency staging (single wave -> no barrier ever needed).
  for (int i = l; i < ROWS * K_; i += 64)
    s_adj[i] = __builtin_nontemporal_load(adjc + (size_t)n0 * K_ + i);

  // DMA stage: move all 64 rows of neighbor k into abuf[bf]. 16 insts x 1KB.
  // Per-row XOR chunk swizzle on the GLOBAL side, linear LDS dest.
  auto stage = [&](int k, int bf) {
#pragma unroll
    for (int j = 0; j < 16; ++j) {
      const int row = j * 4 + (l >> 4);
      const int src_chunk = (l & 15) ^ (row & 7);
      const size_t goff = (size_t)(unsigned)s_adj[row * K_ + k] * ROWB + (src_chunk << 4);
      const char* src = (const char*)xb + goff;
      short* dst = &abuf[bf][(j * 4) * 128];  // wave-uniform base
      __builtin_amdgcn_global_load_lds(
          (const __attribute__((address_space(1))) unsigned int*)src,
          (__attribute__((address_space(3))) unsigned int*)dst, 16, 0, 0);
    }
  };

  // wt B-fragment register prefetch (8 x short8 = 32 VGPR per set, ping-pong).
  const short* wbase = wt + q * 8 + (c << 6);
  short8 rw[2][8];
  auto wload = [&](int k, int par) {
#pragma unroll
    for (int fs = 0; fs < 2; ++fs)
#pragma unroll
      for (int ct = 0; ct < 4; ++ct)
        rw[par][fs * 4 + ct] = *(const short8*)(wbase + (k << 12) + fs * 32 + (ct << 10));
  };

  f32x4 acc[2][4][4];  // [plane][row-tile][ct]
#pragma unroll
  for (int p = 0; p < 2; ++p)
#pragma unroll
    for (int rt = 0; rt < 4; ++rt)
#pragma unroll
      for (int ct = 0; ct < 4; ++ct)
        acc[p][rt][ct] = (f32x4){0.f, 0.f, 0.f, 0.f};

  // Prologue: W0, S0, W1, S1.
  wload(0, 0);
  stage(0, 0);
  wload(1, 1);
  stage(1, 1);

  // Steady state per iter k: [lgkm fence] W_{k+1}(8) S_{k+2}(16), then
  // s_waitcnt vmcnt(40): 40 newest = {S_{k+1}(16), W_{k+1}(8), S_{k+2}(16)} stay in
  // flight; S_k + W_k guaranteed complete. Tail: vmcnt(24) @k=7, vmcnt(0) @k=8.
#pragma unroll
  for (int k = 0; k < K_; ++k) {
    // Prior ds_reads must complete before DMA may overwrite that buffer.
    asm volatile("s_waitcnt lgkmcnt(0)" ::: "memory");
    if (k >= 1 && k + 1 < K_) wload(k + 1, (k + 1) & 1);
    if (k + 2 < K_) stage(k + 2, (k + 2) % 3);

    if (k <= K_ - 3) {
      asm volatile("s_waitcnt vmcnt(40)" ::: "memory");
    } else if (k == K_ - 2) {
      asm volatile("s_waitcnt vmcnt(24)" ::: "memory");
    } else {
      asm volatile("s_waitcnt vmcnt(0)" ::: "memory");
    }
    __builtin_amdgcn_sched_barrier(0);

    const short* bufk = abuf[k % 3];
#pragma unroll
    for (int fs = 0; fs < 2; ++fs) {
#pragma unroll
      for (int rt = 0; rt < 4; ++rt) {
        const int arow = (rt * 16 + c) * 128;        // lane's A row base (shorts)
        const int ch0 = (fs * 4 + q) ^ (c & 7);      // plane 0 chunk (swizzled)
        const int ch1 = (8 + fs * 4 + q) ^ (c & 7);  // plane 1 chunk
        const short8 a0 = *(const short8*)&bufk[arow + (ch0 << 3)];
        const short8 a1 = *(const short8*)&bufk[arow + (ch1 << 3)];
#pragma unroll
        for (int ct = 0; ct < 4; ++ct) {
          const short8 bfr = rw[k & 1][fs * 4 + ct];
          acc[0][rt][ct] =
              __builtin_amdgcn_mfma_f32_16x16x32_bf16(a0, bfr, acc[0][rt][ct], 0, 0, 0);
          acc[1][rt][ct] =
              __builtin_amdgcn_mfma_f32_16x16x32_bf16(a1, bfr, acc[1][rt][ct], 0, 0, 0);
        }
      }
    }
  }

  // Epilogue: C col = lane&15, row-in-tile = quad*4 + reg; nontemporal stores.
  float bv[4];
#pragma unroll
  for (int ct = 0; ct < 4; ++ct) bv[ct] = bias[ct * 16 + c];

#pragma unroll
  for (int p = 0; p < 2; ++p) {
    const size_t outbase = ((size_t)p * N_ + (size_t)n0) * F_;
#pragma unroll
    for (int rt = 0; rt < 4; ++rt) {
#pragma unroll
      for (int ct = 0; ct < 4; ++ct) {
#pragma unroll
        for (int rr = 0; rr < 4; ++rr) {
          const int row = rt * 16 + q * 4 + rr;
          __builtin_nontemporal_store(acc[p][rt][ct][rr] + bv[ct],
                                      &out[outbase + (size_t)row * F_ + ct * 16 + c]);
        }
      }
    }
  }
}

extern "C" void kernel_launch(void* const* d_in, const int* in_sizes, int n_in,
                              void* d_out, int out_size, void* d_ws, size_t ws_size,
                              hipStream_t stream) {
  const float* x = (const float*)d_in[0];
  const int* adjc = (const int*)d_in[1];
  const float* W = (const float*)d_in[2];
  const float* bias = (const float*)d_in[3];
  float* out = (float*)d_out;

  unsigned short* xb = (unsigned short*)d_ws;  // 50,331,648 B
  unsigned short* wt = (unsigned short*)((char*)d_ws + (size_t)B_ * N_ * F_ * 2);

  cvt_x_kernel<<<dim3(N_ * 16 / 256, B_), 256, 0, stream>>>(x, xb);
  cvt_w_kernel<<<144, 256, 0, stream>>>(W, wt);

  nhconv_main<<<N_ / ROWS, 64, 0, stream>>>((const short*)xb, adjc, (const short*)wt,
                                            bias, out);
}